// Round 11
// baseline (93.678 us; speedup 1.0000x reference)
//
#include <hip/hip_runtime.h>
#include <math.h>

#define B_N 4096
#define L_N 16
#define NJC 64             // j-chunks (grid.y); 16 x 64 = 1024 blocks
#define CSTRIDE 48         // floats per j record: [0:16)=A [16:32)=B [32:48)=C

#define NHALF_LOG2E 0.7213475204444817f   // 0.5 * log2(e)
#define LOG2E_F     1.4426950408889634f
#define LN2_F       0.6931471805599453f
#define LOG_2PI_F   1.8378770664093453f

typedef float f32x2 __attribute__((ext_vector_type(2)));
typedef int   i32x2 __attribute__((ext_vector_type(2)));

// ws layout (floats):
//   coef : [B_N][CSTRIDE]    (768 KB, L2-resident)
//   part : [njc][17][B_N]    per-chunk partials (0..15 = per-l exp2 sums, 16 = sum2)
//   part2: [17][B_N]         chunk-summed

// ---- coefficients: logq2(i,j,l) = A*z^2 + B*z + C (log2 domain); also zero out ----
extern "C" __global__ __launch_bounds__(256)
void btc_coef(const float* __restrict__ zm, const float* __restrict__ zlv,
              float* __restrict__ coef, float* __restrict__ out) {
    const int g = blockIdx.x * 256 + threadIdx.x;   // 65536 = B_N * L_N
    if (g == 0) out[0] = 0.0f;                      // atomic target for btc_fin
    const int j = g >> 4, l = g & 15;
    float M  = zm[g];
    float lv = zlv[g];
    float A  = -NHALF_LOG2E * __builtin_amdgcn_exp2f(-LOG2E_F * lv);
    float Bc = -2.0f * A * M;
    float C  = fmaf(A, M * M, -NHALF_LOG2E * (lv + LOG_2PI_F));
    float* r = coef + (size_t)j * CSTRIDE;
    r[l] = A; r[16 + l] = Bc; r[32 + l] = C;
}

// ---- main: thread owns i; j-range block-uniform -> coefficients via s_load.
//      exp2 computed on the VALU (no transcendental pipe):
//        lg = k + f;  2^lg = poly4(f) * 2^k  via exponent-field integer add.
//      magic = 1.5*2^23: bits(lg+magic)<<23 == k<<23 exactly (magic low 9 bits = 0).
extern "C" __global__ __launch_bounds__(256, 4)
void btc_main(const float* __restrict__ z, const float* __restrict__ coef,
              float* __restrict__ part, int jc /* j's per chunk */) {
    const int i  = blockIdx.x * 256 + threadIdx.x;
    const int jb = blockIdx.y * jc;                 // block-uniform (SGPR path)

    // loop-invariant poly/exp constants -> VGPR-resident splats
    const f32x2 vMAGIC = {12582912.0f, 12582912.0f};   // 1.5 * 2^23
    const f32x2 vCLAMP = {-124.0f, -124.0f};           // keep 2^k in normal range
    const f32x2 vP1 = {0.693147182f,  0.693147182f};   // ln2
    const f32x2 vP2 = {0.240226507f,  0.240226507f};   // ln2^2/2
    const f32x2 vP3 = {0.0555041087f, 0.0555041087f};  // ln2^3/6
    const f32x2 vP4 = {0.00961812910f,0.00961812910f}; // ln2^4/24
    const f32x2 vONE = {1.0f, 1.0f};

    f32x2 z2[8], u2[8], acc[8];
    {
        const float4* zp = (const float4*)(z + (size_t)i * L_N);
        #pragma unroll
        for (int q = 0; q < 4; ++q) {
            float4 v = zp[q];
            z2[2*q]   = (f32x2){v.x, v.y};
            z2[2*q+1] = (f32x2){v.z, v.w};
        }
    }
    #pragma unroll
    for (int q = 0; q < 8; ++q) { u2[q] = z2[q] * z2[q]; acc[q] = (f32x2){0.f, 0.f}; }
    float sum2 = 0.0f;   // diag term keeps this > 0; no max tracking needed

    const float* cj = coef + (size_t)jb * CSTRIDE;
    for (int jj = 0; jj < jc; ++jj, cj += CSTRIDE) {
        f32x2 prod = vONE;
        #pragma unroll
        for (int q = 0; q < 8; ++q) {
            // cj uniform -> s_load; each pk op reads <=1 scalar operand
            f32x2 Av = {cj[2*q],      cj[2*q + 1]};
            f32x2 Bv = {cj[16 + 2*q], cj[16 + 2*q + 1]};
            f32x2 Cv = {cj[32 + 2*q], cj[32 + 2*q + 1]};
            f32x2 t  = Bv * z2[q];          // v_pk_mul_f32 (1 sgpr)
            t        = Av * u2[q] + t;      // v_pk_fma_f32 (1 sgpr)
            f32x2 lg = t + Cv;              // v_pk_add_f32 (1 sgpr)
            lg = __builtin_elementwise_max(lg, vCLAMP);
            f32x2 tt = lg + vMAGIC;         // round-to-int in mantissa
            f32x2 kf = tt - vMAGIC;         // k as float
            f32x2 f  = lg - kf;             // f in [-0.5, 0.5]
            f32x2 p  = vP3 + f * vP4;       // quartic 2^f, rel err ~3e-5
            p        = vP2 + f * p;
            p        = vP1 + f * p;
            p        = vONE + f * p;
            i32x2 eb = __builtin_bit_cast(i32x2, p) +
                       (__builtin_bit_cast(i32x2, tt) << 23);   // + k<<23
            f32x2 e  = __builtin_bit_cast(f32x2, eb);
            acc[q] += e;
            prod   *= e;                    // exp2(sum_l lg) = prod_l exp2(lg)
        }
        sum2 += prod.x * prod.y;
    }

    float* base = part + (size_t)blockIdx.y * 17 * B_N + i;
    #pragma unroll
    for (int q = 0; q < 8; ++q) {
        base[(size_t)(2*q)     * B_N] = acc[q].x;
        base[(size_t)(2*q + 1) * B_N] = acc[q].y;
    }
    base[(size_t)16 * B_N] = sum2;
}

// ---- sum partials over chunks (wide grid, coalesced) ----
extern "C" __global__ __launch_bounds__(256)
void btc_sum(const float* __restrict__ part, float* __restrict__ part2, int njc) {
    const int g = blockIdx.x * 256 + threadIdx.x;   // 17*B_N elems
    float s = 0.0f;
    for (int c = 0; c < njc; ++c) s += part[(size_t)c * 17 * B_N + g];
    part2[g] = s;
}

// ---- finish per-i logs, global mean via one atomic per block ----
extern "C" __global__ __launch_bounds__(256)
void btc_fin(const float* __restrict__ part2, float* __restrict__ out) {
    const int tid = threadIdx.x;
    const int i   = blockIdx.x * 256 + tid;

    float lqprod2 = 0.0f;
    #pragma unroll
    for (int l = 0; l < L_N; ++l)
        lqprod2 += __builtin_amdgcn_logf(part2[(size_t)l * B_N + i]);
    float v = LN2_F * (__builtin_amdgcn_logf(part2[(size_t)16 * B_N + i]) - lqprod2);

    #pragma unroll
    for (int off = 32; off > 0; off >>= 1) v += __shfl_down(v, off);
    __shared__ float red[4];
    const int lane = tid & 63, w = tid >> 6;
    if (lane == 0) red[w] = v;
    __syncthreads();
    if (tid == 0)
        atomicAdd(out, ((red[0] + red[1]) + (red[2] + red[3])) * (1.0f / (float)B_N));
}

extern "C" void kernel_launch(void* const* d_in, const int* in_sizes, int n_in,
                              void* d_out, int out_size, void* d_ws, size_t ws_size,
                              hipStream_t stream) {
    const float* z   = (const float*)d_in[0];
    const float* zm  = (const float*)d_in[1];
    const float* zlv = (const float*)d_in[2];
    float* out  = (float*)d_out;
    float* coef = (float*)d_ws;
    float* part = coef + (size_t)B_N * CSTRIDE;

    int njc = NJC;
    while (njc > 1) {
        size_t need = ((size_t)B_N * CSTRIDE + (size_t)njc * 17 * B_N + 17 * B_N)
                      * sizeof(float);
        if (need <= ws_size) break;
        njc >>= 1;
    }
    const int jc = B_N / njc;
    float* part2 = part + (size_t)njc * 17 * B_N;

    hipLaunchKernelGGL(btc_coef, dim3(B_N * L_N / 256), dim3(256), 0, stream,
                       zm, zlv, coef, out);
    hipLaunchKernelGGL(btc_main, dim3(B_N / 256, njc), dim3(256), 0, stream,
                       z, coef, part, jc);
    hipLaunchKernelGGL(btc_sum, dim3(17 * B_N / 256), dim3(256), 0, stream,
                       part, part2, njc);
    hipLaunchKernelGGL(btc_fin, dim3(B_N / 256), dim3(256), 0, stream,
                       part2, out);
}

// Round 12
// 87.378 us; speedup vs baseline: 1.0721x; 1.0721x over previous
//
#include <hip/hip_runtime.h>
#include <math.h>

#define B_N 4096
#define L_N 16
#define NJC 128            // j-chunks (grid.y); 16 x 128 = 2048 blocks = 8/CU = 8 waves/SIMD
#define CSTRIDE 48         // floats per j record: [0:16)=A [16:32)=B [32:48)=C

#define NHALF_LOG2E 0.7213475204444817f   // 0.5 * log2(e)
#define LOG2E_F     1.4426950408889634f
#define LN2_F       0.6931471805599453f
#define LOG_2PI_F   1.8378770664093453f

typedef float f32x2 __attribute__((ext_vector_type(2)));

// ws layout (floats):
//   coef : [B_N][CSTRIDE]    (768 KB, L2-resident)
//   part : [njc][17][B_N]    per-chunk partials (0..15 = per-l exp2 sums, 16 = sum2)
//   part2: [17][B_N]         chunk-summed

// ---- coefficients: logq2(i,j,l) = A*z^2 + B*z + C (log2 domain); also zero out ----
extern "C" __global__ __launch_bounds__(256)
void btc_coef(const float* __restrict__ zm, const float* __restrict__ zlv,
              float* __restrict__ coef, float* __restrict__ out) {
    const int g = blockIdx.x * 256 + threadIdx.x;   // 65536 = B_N * L_N
    if (g == 0) out[0] = 0.0f;                      // atomic target for btc_fin
    const int j = g >> 4, l = g & 15;
    float M  = zm[g];
    float lv = zlv[g];
    float A  = -NHALF_LOG2E * __builtin_amdgcn_exp2f(-LOG2E_F * lv);
    float Bc = -2.0f * A * M;
    float C  = fmaf(A, M * M, -NHALF_LOG2E * (lv + LOG_2PI_F));
    float* r = coef + (size_t)j * CSTRIDE;
    r[l] = A; r[16 + l] = Bc; r[32 + l] = C;
}

// ---- main: thread owns i; j-range block-uniform -> coefficients via s_load.
//      8 waves/SIMD hide the s_load (L2 ~200cy) + v_exp dependency chains. ----
extern "C" __global__ __launch_bounds__(256, 4)
void btc_main(const float* __restrict__ z, const float* __restrict__ coef,
              float* __restrict__ part, int jc /* j's per chunk */) {
    const int i  = blockIdx.x * 256 + threadIdx.x;
    const int jb = blockIdx.y * jc;                 // block-uniform (SGPR path)

    f32x2 z2[8], u2[8], acc[8];
    {
        const float4* zp = (const float4*)(z + (size_t)i * L_N);
        #pragma unroll
        for (int q = 0; q < 4; ++q) {
            float4 v = zp[q];
            z2[2*q]   = (f32x2){v.x, v.y};
            z2[2*q+1] = (f32x2){v.z, v.w};
        }
    }
    #pragma unroll
    for (int q = 0; q < 8; ++q) { u2[q] = z2[q] * z2[q]; acc[q] = (f32x2){0.f, 0.f}; }
    float sum2 = 0.0f;   // diag term keeps this > 0; no max tracking needed

    const float* cj = coef + (size_t)jb * CSTRIDE;
    for (int jj = 0; jj < jc; ++jj, cj += CSTRIDE) {
        f32x2 prod = (f32x2){1.f, 1.f};
        #pragma unroll
        for (int q = 0; q < 8; ++q) {
            // cj uniform -> s_load_dwordx16; each pk op reads exactly 1 scalar pair
            f32x2 Av = {cj[2*q],      cj[2*q + 1]};
            f32x2 Bv = {cj[16 + 2*q], cj[16 + 2*q + 1]};
            f32x2 Cv = {cj[32 + 2*q], cj[32 + 2*q + 1]};
            f32x2 t  = Bv * z2[q];          // v_pk_mul_f32 (1 sgpr)
            t        = Av * u2[q] + t;      // v_pk_fma_f32 (1 sgpr)
            f32x2 lg = t + Cv;              // v_pk_add_f32 (1 sgpr)
            f32x2 e  = (f32x2){__builtin_amdgcn_exp2f(lg.x),
                               __builtin_amdgcn_exp2f(lg.y)};
            acc[q] += e;
            prod   *= e;                    // exp2(sum_l lg) = prod_l exp2(lg)
        }
        sum2 += prod.x * prod.y;
    }

    float* base = part + (size_t)blockIdx.y * 17 * B_N + i;
    #pragma unroll
    for (int q = 0; q < 8; ++q) {
        base[(size_t)(2*q)     * B_N] = acc[q].x;
        base[(size_t)(2*q + 1) * B_N] = acc[q].y;
    }
    base[(size_t)16 * B_N] = sum2;
}

// ---- sum partials over chunks (wide grid, coalesced) ----
extern "C" __global__ __launch_bounds__(256)
void btc_sum(const float* __restrict__ part, float* __restrict__ part2, int njc) {
    const int g = blockIdx.x * 256 + threadIdx.x;   // 17*B_N elems
    float s = 0.0f;
    for (int c = 0; c < njc; ++c) s += part[(size_t)c * 17 * B_N + g];
    part2[g] = s;
}

// ---- finish per-i logs, global mean via one atomic per block ----
extern "C" __global__ __launch_bounds__(256)
void btc_fin(const float* __restrict__ part2, float* __restrict__ out) {
    const int tid = threadIdx.x;
    const int i   = blockIdx.x * 256 + tid;

    float lqprod2 = 0.0f;
    #pragma unroll
    for (int l = 0; l < L_N; ++l)
        lqprod2 += __builtin_amdgcn_logf(part2[(size_t)l * B_N + i]);
    float v = LN2_F * (__builtin_amdgcn_logf(part2[(size_t)16 * B_N + i]) - lqprod2);

    #pragma unroll
    for (int off = 32; off > 0; off >>= 1) v += __shfl_down(v, off);
    __shared__ float red[4];
    const int lane = tid & 63, w = tid >> 6;
    if (lane == 0) red[w] = v;
    __syncthreads();
    if (tid == 0)
        atomicAdd(out, ((red[0] + red[1]) + (red[2] + red[3])) * (1.0f / (float)B_N));
}

extern "C" void kernel_launch(void* const* d_in, const int* in_sizes, int n_in,
                              void* d_out, int out_size, void* d_ws, size_t ws_size,
                              hipStream_t stream) {
    const float* z   = (const float*)d_in[0];
    const float* zm  = (const float*)d_in[1];
    const float* zlv = (const float*)d_in[2];
    float* out  = (float*)d_out;
    float* coef = (float*)d_ws;
    float* part = coef + (size_t)B_N * CSTRIDE;

    int njc = NJC;
    while (njc > 1) {
        size_t need = ((size_t)B_N * CSTRIDE + (size_t)njc * 17 * B_N + 17 * B_N)
                      * sizeof(float);
        if (need <= ws_size) break;
        njc >>= 1;
    }
    const int jc = B_N / njc;
    float* part2 = part + (size_t)njc * 17 * B_N;

    hipLaunchKernelGGL(btc_coef, dim3(B_N * L_N / 256), dim3(256), 0, stream,
                       zm, zlv, coef, out);
    hipLaunchKernelGGL(btc_main, dim3(B_N / 256, njc), dim3(256), 0, stream,
                       z, coef, part, jc);
    hipLaunchKernelGGL(btc_sum, dim3(17 * B_N / 256), dim3(256), 0, stream,
                       part, part2, njc);
    hipLaunchKernelGGL(btc_fin, dim3(B_N / 256), dim3(256), 0, stream,
                       part2, out);
}

// Round 13
// 65.049 us; speedup vs baseline: 1.4401x; 1.3433x over previous
//
#include <hip/hip_runtime.h>
#include <math.h>

#define B_N 4096
#define L_N 16
#define NJC 128            // j-chunks; grid = (4096/1024) x 128 = 512 blocks = 2/CU
#define BT  1024           // block threads: 16 waves share one j-stream (K$ locality)
#define CSTRIDE 48         // floats per j record: [0:16)=A [16:32)=B [32:48)=C

#define NHALF_LOG2E 0.7213475204444817f   // 0.5 * log2(e)
#define LOG2E_F     1.4426950408889634f
#define LN2_F       0.6931471805599453f
#define LOG_2PI_F   1.8378770664093453f

typedef float f32x2 __attribute__((ext_vector_type(2)));

// ws layout (floats):
//   coef : [B_N][CSTRIDE]    (768 KB, L2-resident)
//   part : [njc][17][B_N]    per-chunk partials (0..15 = per-l exp2 sums, 16 = sum2)
//   part2: [17][B_N]         chunk-summed

// ---- coefficients: logq2(i,j,l) = A*z^2 + B*z + C (log2 domain); also zero out ----
extern "C" __global__ __launch_bounds__(256)
void btc_coef(const float* __restrict__ zm, const float* __restrict__ zlv,
              float* __restrict__ coef, float* __restrict__ out) {
    const int g = blockIdx.x * 256 + threadIdx.x;   // 65536 = B_N * L_N
    if (g == 0) out[0] = 0.0f;                      // atomic target for btc_fin
    const int j = g >> 4, l = g & 15;
    float M  = zm[g];
    float lv = zlv[g];
    float A  = -NHALF_LOG2E * __builtin_amdgcn_exp2f(-LOG2E_F * lv);
    float Bc = -2.0f * A * M;
    float C  = fmaf(A, M * M, -NHALF_LOG2E * (lv + LOG_2PI_F));
    float* r = coef + (size_t)j * CSTRIDE;
    r[l] = A; r[16 + l] = Bc; r[32 + l] = C;
}

// ---- main: thread owns i; 16 waves/block share one block-uniform j-stream ----
extern "C" __global__ __launch_bounds__(BT, 8)
void btc_main(const float* __restrict__ z, const float* __restrict__ coef,
              float* __restrict__ part, int jc /* j's per chunk */) {
    const int i  = blockIdx.x * BT + threadIdx.x;
    const int jb = blockIdx.y * jc;                 // block-uniform (SGPR path)

    f32x2 z2[8], u2[8], acc[8];
    {
        const float4* zp = (const float4*)(z + (size_t)i * L_N);
        #pragma unroll
        for (int q = 0; q < 4; ++q) {
            float4 v = zp[q];
            z2[2*q]   = (f32x2){v.x, v.y};
            z2[2*q+1] = (f32x2){v.z, v.w};
        }
    }
    #pragma unroll
    for (int q = 0; q < 8; ++q) { u2[q] = z2[q] * z2[q]; acc[q] = (f32x2){0.f, 0.f}; }
    float sum2 = 0.0f;   // diag term keeps this > 0; no max tracking needed

    const float* cj = coef + (size_t)jb * CSTRIDE;
    for (int jj = 0; jj < jc; ++jj, cj += CSTRIDE) {
        f32x2 prod = (f32x2){1.f, 1.f};
        #pragma unroll
        for (int q = 0; q < 8; ++q) {
            // cj uniform -> s_load_dwordx16; each pk op reads exactly 1 scalar pair
            f32x2 Av = {cj[2*q],      cj[2*q + 1]};
            f32x2 Bv = {cj[16 + 2*q], cj[16 + 2*q + 1]};
            f32x2 Cv = {cj[32 + 2*q], cj[32 + 2*q + 1]};
            f32x2 t  = Bv * z2[q];          // v_pk_mul_f32 (1 sgpr)
            t        = Av * u2[q] + t;      // v_pk_fma_f32 (1 sgpr)
            f32x2 lg = t + Cv;              // v_pk_add_f32 (1 sgpr)
            f32x2 e  = (f32x2){__builtin_amdgcn_exp2f(lg.x),
                               __builtin_amdgcn_exp2f(lg.y)};
            acc[q] += e;
            prod   *= e;                    // exp2(sum_l lg) = prod_l exp2(lg)
        }
        sum2 += prod.x * prod.y;
    }

    float* base = part + (size_t)blockIdx.y * 17 * B_N + i;
    #pragma unroll
    for (int q = 0; q < 8; ++q) {
        base[(size_t)(2*q)     * B_N] = acc[q].x;
        base[(size_t)(2*q + 1) * B_N] = acc[q].y;
    }
    base[(size_t)16 * B_N] = sum2;
}

// ---- sum partials over chunks: 8 independent accumulators (latency-pipelined) ----
extern "C" __global__ __launch_bounds__(256)
void btc_sum(const float* __restrict__ part, float* __restrict__ part2, int njc) {
    const int g = blockIdx.x * 256 + threadIdx.x;   // 17*B_N elems
    const size_t cs = (size_t)17 * B_N;
    float s0 = 0.f, s1 = 0.f, s2 = 0.f, s3 = 0.f;
    float s4 = 0.f, s5 = 0.f, s6 = 0.f, s7 = 0.f;
    int c = 0;
    for (; c + 8 <= njc; c += 8) {
        const float* b = part + (size_t)c * cs + g;
        s0 += b[0 * cs]; s1 += b[1 * cs]; s2 += b[2 * cs]; s3 += b[3 * cs];
        s4 += b[4 * cs]; s5 += b[5 * cs]; s6 += b[6 * cs]; s7 += b[7 * cs];
    }
    for (; c < njc; ++c) s0 += part[(size_t)c * cs + g];
    part2[g] = ((s0 + s1) + (s2 + s3)) + ((s4 + s5) + (s6 + s7));
}

// ---- finish per-i logs, global mean via one atomic per block ----
extern "C" __global__ __launch_bounds__(256)
void btc_fin(const float* __restrict__ part2, float* __restrict__ out) {
    const int tid = threadIdx.x;
    const int i   = blockIdx.x * 256 + tid;

    float lqprod2 = 0.0f;
    #pragma unroll
    for (int l = 0; l < L_N; ++l)
        lqprod2 += __builtin_amdgcn_logf(part2[(size_t)l * B_N + i]);
    float v = LN2_F * (__builtin_amdgcn_logf(part2[(size_t)16 * B_N + i]) - lqprod2);

    #pragma unroll
    for (int off = 32; off > 0; off >>= 1) v += __shfl_down(v, off);
    __shared__ float red[4];
    const int lane = tid & 63, w = tid >> 6;
    if (lane == 0) red[w] = v;
    __syncthreads();
    if (tid == 0)
        atomicAdd(out, ((red[0] + red[1]) + (red[2] + red[3])) * (1.0f / (float)B_N));
}

extern "C" void kernel_launch(void* const* d_in, const int* in_sizes, int n_in,
                              void* d_out, int out_size, void* d_ws, size_t ws_size,
                              hipStream_t stream) {
    const float* z   = (const float*)d_in[0];
    const float* zm  = (const float*)d_in[1];
    const float* zlv = (const float*)d_in[2];
    float* out  = (float*)d_out;
    float* coef = (float*)d_ws;
    float* part = coef + (size_t)B_N * CSTRIDE;

    int njc = NJC;
    while (njc > 1) {
        size_t need = ((size_t)B_N * CSTRIDE + (size_t)njc * 17 * B_N + 17 * B_N)
                      * sizeof(float);
        if (need <= ws_size) break;
        njc >>= 1;
    }
    const int jc = B_N / njc;
    float* part2 = part + (size_t)njc * 17 * B_N;

    hipLaunchKernelGGL(btc_coef, dim3(B_N * L_N / 256), dim3(256), 0, stream,
                       zm, zlv, coef, out);
    hipLaunchKernelGGL(btc_main, dim3(B_N / BT, njc), dim3(BT), 0, stream,
                       z, coef, part, jc);
    hipLaunchKernelGGL(btc_sum, dim3(17 * B_N / 256), dim3(256), 0, stream,
                       part, part2, njc);
    hipLaunchKernelGGL(btc_fin, dim3(B_N / 256), dim3(256), 0, stream,
                       part2, out);
}

// Round 14
// 58.188 us; speedup vs baseline: 1.6099x; 1.1179x over previous
//
#include <hip/hip_runtime.h>
#include <math.h>

#define B_N 4096
#define L_N 16
#define NJC 64             // j-chunks (grid.y): grid = 32 x 64 = 2048 blocks = 8/CU
#define R_I 2              // sample rows per lane
#define IPB 128            // i's per block: 64 lanes x R_I
#define NW  4              // waves per block; each takes JT/NW j's of the staged tile
#define JT  64             // j's per staged LDS tile
#define JPW (JT / NW)      // 16

#define NHALF_LOG2E 0.7213475204444817f   // 0.5 * log2(e)
#define LOG2E_F     1.4426950408889634f
#define LN2_F       0.6931471805599453f
#define LOG_2PI_F   1.8378770664093453f

typedef float f32x2 __attribute__((ext_vector_type(2)));

// LDS: staging sA/sB/sC (3*1024 floats = 12 KB) aliased with the two-pass
// combine buffer red[NW][17][64] (17408 B block LDS -> 8 blocks/CU possible).
#define LDSF (NW * 17 * 64)

// ws layout (floats):
//   part : [njc][17][B_N]   per-chunk partials (0..15 = per-l exp2 sums, 16 = sum2)
//   part2: [17][B_N]        chunk-summed

// launch_bounds(256,4): VGPR cap 128. R5 measured this inner loop at 56 VGPR;
// (256,5)'s cap ~102 paradoxically produced 48 VGPR + scratch spill (R9:
// FETCH 5.8 MB). Cap 128 -> natural ~56, no spill, 8 blocks/CU by LDS/threads.
extern "C" __global__ __launch_bounds__(256, 4)
void btc_main(const float* __restrict__ z, const float* __restrict__ zm,
              const float* __restrict__ zlv, float* __restrict__ part,
              int jc /* j's per chunk, multiple of JT */) {
    __shared__ __align__(16) float lds[LDSF];
    float* sA = lds;                    // [JT*L_N]
    float* sB = lds + JT * L_N;
    float* sC = lds + 2 * JT * L_N;
    float (*red)[17][64] = (float (*)[17][64])lds;

    const int tid  = threadIdx.x;
    const int lane = tid & 63;
    const int w    = tid >> 6;

    // two sample rows per lane: i = blockIdx.x*IPB + r*64 + lane
    f32x2 zr[R_I][8], acc[R_I][8];
    float sum2[R_I];
    #pragma unroll
    for (int r = 0; r < R_I; ++r) {
        const float4* zp = (const float4*)(z + (size_t)(blockIdx.x * IPB + r * 64 + lane) * L_N);
        #pragma unroll
        for (int q = 0; q < 4; ++q) {
            float4 v = zp[q];
            zr[r][2*q]   = (f32x2){v.x, v.y};
            zr[r][2*q+1] = (f32x2){v.z, v.w};
            acc[r][2*q]   = (f32x2){0.f, 0.f};
            acc[r][2*q+1] = (f32x2){0.f, 0.f};
        }
        sum2[r] = 0.0f;   // diag term keeps this > 0; no max tracking needed
    }

    for (int t = 0; t < jc / JT; ++t) {
        __syncthreads();   // previous tile fully consumed
        const size_t gbase = ((size_t)blockIdx.y * jc + (size_t)t * JT) * L_N;
        {   // stage + transform JT j's: 1024 elems/array = one float4 per thread
            const int e4 = tid * 4;
            float4 m4 = *(const float4*)(zm  + gbase + e4);
            float4 v4 = *(const float4*)(zlv + gbase + e4);
            float4 a4, b4, c4;
            float A;
            A = -NHALF_LOG2E * __builtin_amdgcn_exp2f(-LOG2E_F * v4.x);
            a4.x = A; b4.x = -2.0f * A * m4.x;
            c4.x = fmaf(A, m4.x * m4.x, -NHALF_LOG2E * (v4.x + LOG_2PI_F));
            A = -NHALF_LOG2E * __builtin_amdgcn_exp2f(-LOG2E_F * v4.y);
            a4.y = A; b4.y = -2.0f * A * m4.y;
            c4.y = fmaf(A, m4.y * m4.y, -NHALF_LOG2E * (v4.y + LOG_2PI_F));
            A = -NHALF_LOG2E * __builtin_amdgcn_exp2f(-LOG2E_F * v4.z);
            a4.z = A; b4.z = -2.0f * A * m4.z;
            c4.z = fmaf(A, m4.z * m4.z, -NHALF_LOG2E * (v4.z + LOG_2PI_F));
            A = -NHALF_LOG2E * __builtin_amdgcn_exp2f(-LOG2E_F * v4.w);
            a4.w = A; b4.w = -2.0f * A * m4.w;
            c4.w = fmaf(A, m4.w * m4.w, -NHALF_LOG2E * (v4.w + LOG_2PI_F));
            *(float4*)&sA[e4] = a4;
            *(float4*)&sB[e4] = b4;
            *(float4*)&sC[e4] = c4;
        }
        __syncthreads();

        for (int jj = 0; jj < JPW; ++jj) {
            const int jo = (w * JPW + jj) * L_N;
            const float4* pA = (const float4*)&sA[jo];
            const float4* pB = (const float4*)&sB[jo];
            const float4* pC = (const float4*)&sC[jo];
            f32x2 prod[R_I];
            #pragma unroll
            for (int r = 0; r < R_I; ++r) prod[r] = (f32x2){1.f, 1.f};
            #pragma unroll
            for (int q = 0; q < 4; ++q) {
                float4 A4 = pA[q], B4 = pB[q], C4 = pC[q];   // uniform -> LDS broadcast
                f32x2 A0 = {A4.x, A4.y}, A1 = {A4.z, A4.w};
                f32x2 B0 = {B4.x, B4.y}, B1 = {B4.z, B4.w};
                f32x2 C0 = {C4.x, C4.y}, C1 = {C4.z, C4.w};
                #pragma unroll
                for (int r = 0; r < R_I; ++r) {
                    f32x2 tv, lg, e;
                    tv = A0 * zr[r][2*q] + B0;  lg = tv * zr[r][2*q] + C0;
                    e  = (f32x2){__builtin_amdgcn_exp2f(lg.x), __builtin_amdgcn_exp2f(lg.y)};
                    acc[r][2*q] += e;  prod[r] *= e;
                    tv = A1 * zr[r][2*q+1] + B1; lg = tv * zr[r][2*q+1] + C1;
                    e  = (f32x2){__builtin_amdgcn_exp2f(lg.x), __builtin_amdgcn_exp2f(lg.y)};
                    acc[r][2*q+1] += e;  prod[r] *= e;
                }
            }
            // exp2(sum_l lg) == prod_l exp2(lg): reuse the 16 per-l exps
            #pragma unroll
            for (int r = 0; r < R_I; ++r)
                sum2[r] += prod[r].x * prod[r].y;
        }
    }

    // combine: 2 passes of 64 i's (row r), red[4][17][64] aliases the staging
    float* bbase = part + (size_t)blockIdx.y * 17 * B_N + blockIdx.x * IPB;
    #pragma unroll
    for (int r = 0; r < R_I; ++r) {
        __syncthreads();   // staging reads (r=0) / previous pass reads (r=1) done
        #pragma unroll
        for (int q = 0; q < 8; ++q) {
            red[w][2*q][lane]     = acc[r][q].x;
            red[w][2*q + 1][lane] = acc[r][q].y;
        }
        red[w][16][lane] = sum2[r];
        __syncthreads();
        if (tid < 64) {
            #pragma unroll
            for (int f = 0; f < 17; ++f) {
                float v = (red[0][f][tid] + red[1][f][tid]) +
                          (red[2][f][tid] + red[3][f][tid]);
                bbase[(size_t)f * B_N + r * 64 + tid] = v;
            }
        }
    }
}

// ---- sum partials over chunks: 8 independent accumulators (latency-pipelined) ----
extern "C" __global__ __launch_bounds__(256)
void btc_sum(const float* __restrict__ part, float* __restrict__ part2, int njc) {
    const int g = blockIdx.x * 256 + threadIdx.x;   // 17*B_N elems
    const size_t cs = (size_t)17 * B_N;
    float s0 = 0.f, s1 = 0.f, s2 = 0.f, s3 = 0.f;
    float s4 = 0.f, s5 = 0.f, s6 = 0.f, s7 = 0.f;
    int c = 0;
    for (; c + 8 <= njc; c += 8) {
        const float* b = part + (size_t)c * cs + g;
        s0 += b[0 * cs]; s1 += b[1 * cs]; s2 += b[2 * cs]; s3 += b[3 * cs];
        s4 += b[4 * cs]; s5 += b[5 * cs]; s6 += b[6 * cs]; s7 += b[7 * cs];
    }
    for (; c < njc; ++c) s0 += part[(size_t)c * cs + g];
    part2[g] = ((s0 + s1) + (s2 + s3)) + ((s4 + s5) + (s6 + s7));
}

// ---- finish per-i logs, global mean via one atomic per block ----
extern "C" __global__ __launch_bounds__(256)
void btc_fin(const float* __restrict__ part2, float* __restrict__ out) {
    const int tid = threadIdx.x;
    const int i   = blockIdx.x * 256 + tid;

    float lqprod2 = 0.0f;
    #pragma unroll
    for (int l = 0; l < L_N; ++l)
        lqprod2 += __builtin_amdgcn_logf(part2[(size_t)l * B_N + i]);
    float v = LN2_F * (__builtin_amdgcn_logf(part2[(size_t)16 * B_N + i]) - lqprod2);

    #pragma unroll
    for (int off = 32; off > 0; off >>= 1) v += __shfl_down(v, off);
    __shared__ float red[4];
    const int lane = tid & 63, w = tid >> 6;
    if (lane == 0) red[w] = v;
    __syncthreads();
    if (tid == 0)
        atomicAdd(out, ((red[0] + red[1]) + (red[2] + red[3])) * (1.0f / (float)B_N));
}

extern "C" void kernel_launch(void* const* d_in, const int* in_sizes, int n_in,
                              void* d_out, int out_size, void* d_ws, size_t ws_size,
                              hipStream_t stream) {
    const float* z   = (const float*)d_in[0];
    const float* zm  = (const float*)d_in[1];
    const float* zlv = (const float*)d_in[2];
    float* out  = (float*)d_out;
    float* part = (float*)d_ws;

    int njc = NJC;
    while (njc > 1) {
        size_t need = ((size_t)njc * 17 * B_N + 17 * B_N) * sizeof(float);
        if (need <= ws_size) break;
        njc >>= 1;
    }
    const int jc = B_N / njc;   // >= 64, multiple of JT
    float* part2 = part + (size_t)njc * 17 * B_N;

    hipMemsetAsync(out, 0, sizeof(float), stream);
    hipLaunchKernelGGL(btc_main, dim3(B_N / IPB, njc), dim3(256), 0, stream,
                       z, zm, zlv, part, jc);
    hipLaunchKernelGGL(btc_sum, dim3(17 * B_N / 256), dim3(256), 0, stream,
                       part, part2, njc);
    hipLaunchKernelGGL(btc_fin, dim3(B_N / 256), dim3(256), 0, stream,
                       part2, out);
}